// Round 1
// baseline (837.606 us; speedup 1.0000x reference)
//
#include <hip/hip_runtime.h>
#include <hip/hip_fp16.h>

// out[p][d] = sum_{s<64} PHI[p*64+s] * ctrl[Jm[p*64+s]][d]
// R5: maximize gather MLP. 16 entries/lane, all 16 table gathers issued
// back-to-back into registers BEFORE any consumption (prev version's
// VGPR_Count=24 proved the compiler serialized gathers ~2 at a time).
// ctrl re-packed to fp16 rows @ 8B stride (4 MB, per-XCD-L2-resident,
// no 64B-line crossing).

typedef float v4f __attribute__((ext_vector_type(4)));
typedef int   v4i __attribute__((ext_vector_type(4)));
typedef unsigned int v2u __attribute__((ext_vector_type(2)));

__global__ __launch_bounds__(256) void pack_ctrl_kernel(
    const float* __restrict__ ctrl,
    unsigned int* __restrict__ tbl,   // 2 dwords per row
    int n_ctrl)
{
    const int j = blockIdx.x * blockDim.x + threadIdx.x;
    if (j >= n_ctrl) return;
    const float x = ctrl[j * 3 + 0];
    const float y = ctrl[j * 3 + 1];
    const float z = ctrl[j * 3 + 2];
    __half2 xy = __floats2half2_rn(x, y);
    __half  hz = __float2half_rn(z);
    unsigned int lo;
    __builtin_memcpy(&lo, &xy, 4);
    unsigned short hzs;
    __builtin_memcpy(&hzs, &hz, 2);
    v2u v; v.x = lo; v.y = (unsigned int)hzs;
    ((v2u*)tbl)[j] = v;
}

__global__ __launch_bounds__(256) void thb_gather_kernel(
    const unsigned int* __restrict__ tbl,   // packed fp16 rows, 8B stride
    const float* __restrict__ phi,
    const int*   __restrict__ jm,
    float*       __restrict__ out,
    int total_entries)
{
    const int tid  = blockIdx.x * blockDim.x + threadIdx.x;
    const int base = tid * 16;                      // 16 entries per lane
    if (base >= total_entries) return;

    // --- stream loads: single-use, nontemporal (don't evict the table) ---
    v4i jj[4];
    v4f ph[4];
    #pragma unroll
    for (int q = 0; q < 4; ++q)
        jj[q] = __builtin_nontemporal_load(((const v4i*)(jm + base)) + q);
    #pragma unroll
    for (int q = 0; q < 4; ++q)
        ph[q] = __builtin_nontemporal_load(((const v4f*)(phi + base)) + q);

    // --- issue ALL 16 gathers before touching any result ---
    const v2u* __restrict__ tv = (const v2u*)tbl;
    v2u r[16];
    #pragma unroll
    for (int q = 0; q < 4; ++q) {
        r[q * 4 + 0] = tv[jj[q].x];
        r[q * 4 + 1] = tv[jj[q].y];
        r[q * 4 + 2] = tv[jj[q].z];
        r[q * 4 + 3] = tv[jj[q].w];
    }

    // --- pure-FMA consumption pass (vmcnt staged waits, no round trips) ---
    float sx = 0.f, sy = 0.f, sz = 0.f;
    #pragma unroll
    for (int q = 0; q < 4; ++q) {
        const float w0 = ph[q].x, w1 = ph[q].y, w2 = ph[q].z, w3 = ph[q].w;
        const float w[4] = { w0, w1, w2, w3 };
        #pragma unroll
        for (int k = 0; k < 4; ++k) {
            const v2u rr = r[q * 4 + k];
            const unsigned int lo = rr.x;
            const unsigned int hi = rr.y;
            __half2 xy; __builtin_memcpy(&xy, &lo, 4);
            const unsigned short hzs = (unsigned short)(hi & 0xffffu);
            __half hz; __builtin_memcpy(&hz, &hzs, 2);
            sx += w[k] * __low2float(xy);
            sy += w[k] * __high2float(xy);
            sz += w[k] * __half2float(hz);
        }
    }

    // --- reduce across the 4-lane subgroup that owns this point ---
    #pragma unroll
    for (int off = 2; off; off >>= 1) {
        sx += __shfl_down(sx, off, 4);
        sy += __shfl_down(sy, off, 4);
        sz += __shfl_down(sz, off, 4);
    }

    if ((threadIdx.x & 3) == 0) {
        const int p = base >> 6;                    // point id = base / 64
        out[p * 3 + 0] = sx;
        out[p * 3 + 1] = sy;
        out[p * 3 + 2] = sz;
    }
}

extern "C" void kernel_launch(void* const* d_in, const int* in_sizes, int n_in,
                              void* d_out, int out_size, void* d_ws, size_t ws_size,
                              hipStream_t stream) {
    const float* ctrl = (const float*)d_in[0];   // [N_CTRL, 3] f32
    const float* phi  = (const float*)d_in[1];   // [TOTAL]    f32
    const int*   jm   = (const int*)  d_in[2];   // [TOTAL]    i32
    float* out = (float*)d_out;                  // [P, 3]     f32

    const int n_ctrl = in_sizes[0] / 3;          // 524,288
    const int total  = in_sizes[1];              // 67,108,864

    unsigned int* tbl = (unsigned int*)d_ws;     // 8 B per ctrl row = 4 MB

    {
        dim3 block(256);
        dim3 grid((n_ctrl + 255) / 256);
        hipLaunchKernelGGL(pack_ctrl_kernel, grid, block, 0, stream,
                           ctrl, tbl, n_ctrl);
    }
    {
        const int threads = total / 16;          // 16 entries per thread
        dim3 block(256);
        dim3 grid((threads + 255) / 256);
        hipLaunchKernelGGL(thb_gather_kernel, grid, block, 0, stream,
                           tbl, phi, jm, out, total);
    }
}

// Round 2
// 796.733 us; speedup vs baseline: 1.0513x; 1.0513x over previous
//
#include <hip/hip_runtime.h>
#include <hip/hip_fp16.h>

// out[p][d] = sum_{s<64} PHI[p*64+s] * ctrl[Jm[p*64+s]][d]
// R6: force gather MLP with inline asm. R5 showed hipcc re-serializes
// source-level "issue all loads first" (VGPR=32, only ~2 in flight).
// Here the 8 table gathers are asm global_load_dwordx2 into 8 pinned
// register pairs, drained by ONE asm s_waitcnt vmcnt(0) + sched_barrier(0)
// (rule #18: FMAs hoist past asm waitcnt without the fence).
// ctrl packed to fp16 rows @ 8B stride (4 MB, L2-resident, no line split).

typedef float v4f __attribute__((ext_vector_type(4)));
typedef int   v4i __attribute__((ext_vector_type(4)));
typedef unsigned int v2u __attribute__((ext_vector_type(2)));

__global__ __launch_bounds__(256) void pack_ctrl_kernel(
    const float* __restrict__ ctrl,
    unsigned int* __restrict__ tbl,   // 2 dwords per row
    int n_ctrl)
{
    const int j = blockIdx.x * blockDim.x + threadIdx.x;
    if (j >= n_ctrl) return;
    const float x = ctrl[j * 3 + 0];
    const float y = ctrl[j * 3 + 1];
    const float z = ctrl[j * 3 + 2];
    __half2 xy = __floats2half2_rn(x, y);
    __half  hz = __float2half_rn(z);
    unsigned int lo;
    __builtin_memcpy(&lo, &xy, 4);
    unsigned short hzs;
    __builtin_memcpy(&hzs, &hz, 2);
    v2u v; v.x = lo; v.y = (unsigned int)hzs;
    ((v2u*)tbl)[j] = v;
}

__device__ __forceinline__ v2u issue_gather(const v2u* __restrict__ p)
{
    v2u r;
    // volatile: keep issue order vs the waitcnt asm; no "memory" clobber so
    // the scheduler may still hoist address math, but cannot elide/reorder
    // these relative to the drain below.
    asm volatile("global_load_dwordx2 %0, %1, off" : "=v"(r) : "v"(p));
    return r;
}

__device__ __forceinline__ void consume(const v2u rr, const float w,
                                        float& sx, float& sy, float& sz)
{
    const unsigned int lo = rr.x;
    const unsigned int hi = rr.y;
    __half2 xy; __builtin_memcpy(&xy, &lo, 4);
    const unsigned short hzs = (unsigned short)(hi & 0xffffu);
    __half hz; __builtin_memcpy(&hz, &hzs, 2);
    sx += w * __low2float(xy);
    sy += w * __high2float(xy);
    sz += w * __half2float(hz);
}

__global__ __launch_bounds__(256) void thb_gather_kernel(
    const unsigned int* __restrict__ tbl,   // packed fp16 rows, 8B stride
    const float* __restrict__ phi,
    const int*   __restrict__ jm,
    float*       __restrict__ out,
    int total_entries)
{
    const int tid  = blockIdx.x * blockDim.x + threadIdx.x;
    const int base = tid * 8;                       // 8 entries per lane
    if (base >= total_entries) return;

    // Single-use streams: nontemporal so they don't evict the 4 MB table.
    const v4i jj0 = __builtin_nontemporal_load((const v4i*)(jm + base));
    const v4i jj1 = __builtin_nontemporal_load((const v4i*)(jm + base + 4));
    const v4f ph0 = __builtin_nontemporal_load((const v4f*)(phi + base));
    const v4f ph1 = __builtin_nontemporal_load((const v4f*)(phi + base + 4));

    const v2u* __restrict__ tv = (const v2u*)tbl;

    // Issue all 8 gathers back-to-back; hardware queues them in order.
    v2u r0 = issue_gather(tv + jj0.x);
    v2u r1 = issue_gather(tv + jj0.y);
    v2u r2 = issue_gather(tv + jj0.z);
    v2u r3 = issue_gather(tv + jj0.w);
    v2u r4 = issue_gather(tv + jj1.x);
    v2u r5 = issue_gather(tv + jj1.y);
    v2u r6 = issue_gather(tv + jj1.z);
    v2u r7 = issue_gather(tv + jj1.w);

    // Drain once: 8 outstanding simultaneously -> latency paid once.
    asm volatile("s_waitcnt vmcnt(0)" ::: "memory");
    __builtin_amdgcn_sched_barrier(0);   // rule #18: pin consumers after wait

    float sx = 0.f, sy = 0.f, sz = 0.f;
    consume(r0, ph0.x, sx, sy, sz);
    consume(r1, ph0.y, sx, sy, sz);
    consume(r2, ph0.z, sx, sy, sz);
    consume(r3, ph0.w, sx, sy, sz);
    consume(r4, ph1.x, sx, sy, sz);
    consume(r5, ph1.y, sx, sy, sz);
    consume(r6, ph1.z, sx, sy, sz);
    consume(r7, ph1.w, sx, sy, sz);

    // Reduce across the 8-lane subgroup that owns this point.
    #pragma unroll
    for (int off = 4; off; off >>= 1) {
        sx += __shfl_down(sx, off, 8);
        sy += __shfl_down(sy, off, 8);
        sz += __shfl_down(sz, off, 8);
    }

    if ((threadIdx.x & 7) == 0) {
        const int p = base >> 6;                    // point id = base / 64
        out[p * 3 + 0] = sx;
        out[p * 3 + 1] = sy;
        out[p * 3 + 2] = sz;
    }
}

extern "C" void kernel_launch(void* const* d_in, const int* in_sizes, int n_in,
                              void* d_out, int out_size, void* d_ws, size_t ws_size,
                              hipStream_t stream) {
    const float* ctrl = (const float*)d_in[0];   // [N_CTRL, 3] f32
    const float* phi  = (const float*)d_in[1];   // [TOTAL]    f32
    const int*   jm   = (const int*)  d_in[2];   // [TOTAL]    i32
    float* out = (float*)d_out;                  // [P, 3]     f32

    const int n_ctrl = in_sizes[0] / 3;          // 524,288
    const int total  = in_sizes[1];              // 67,108,864

    unsigned int* tbl = (unsigned int*)d_ws;     // 8 B per ctrl row = 4 MB

    {
        dim3 block(256);
        dim3 grid((n_ctrl + 255) / 256);
        hipLaunchKernelGGL(pack_ctrl_kernel, grid, block, 0, stream,
                           ctrl, tbl, n_ctrl);
    }
    {
        const int threads = total / 8;           // 8 entries per thread
        dim3 block(256);
        dim3 grid((threads + 255) / 256);
        hipLaunchKernelGGL(thb_gather_kernel, grid, block, 0, stream,
                           tbl, phi, jm, out, total);
    }
}